// Round 6
// baseline (8329.823 us; speedup 1.0000x reference)
//
#include <hip/hip_runtime.h>
#include <math.h>

#define B_ 1024
#define T_ 128
#define H_ 2048
#define C_ 10

typedef __bf16 bf16_t;
typedef __bf16 bf16x8 __attribute__((ext_vector_type(8)));
typedef __bf16 bf16x4 __attribute__((ext_vector_type(4)));
typedef float f32x4 __attribute__((ext_vector_type(4)));

// Static device storage (rewritten every call in dependency order):
// bf16 h ping-pong (8 MB), bf16 W_hh^T (8 MB), fp32 split-K partials (8 MB),
// per-tile flags for the kz0->kz1 handoff.
__device__ __align__(16) bf16_t g_hb[2][(size_t)B_ * H_];
__device__ __align__(16) bf16_t g_whhT[(size_t)H_ * H_];
__device__ __align__(16) float  g_part[128][16384];
__device__ int g_flag[128];

__device__ __forceinline__ void gload16(const bf16_t* g, bf16_t* l) {
    __builtin_amdgcn_global_load_lds(
        (const __attribute__((address_space(1))) void*)g,
        (__attribute__((address_space(3))) void*)l, 16, 0, 0);
}

// Counted-vmcnt barrier: retire oldest stages without draining the pipeline.
template <int VM>
__device__ __forceinline__ void wait_vm_barrier() {
    asm volatile("s_waitcnt vmcnt(%0)\n\ts_barrier" :: "n"(VM) : "memory");
}

// One-time: W_hhT[n][k] = bf16(W_hh[k][n]) — B operand must be K-contiguous.
__global__ __launch_bounds__(256) void prep_whhT(const float* __restrict__ Whh) {
    __shared__ float tile[32][33];
    const int i  = threadIdx.x >> 3;
    const int j4 = (threadIdx.x & 7) * 4;
    const int r0 = blockIdx.y * 32;
    const int c0 = blockIdx.x * 32;
    f32x4 v = *(const f32x4*)(Whh + (size_t)(r0 + i) * H_ + c0 + j4);
    tile[i][j4 + 0] = v[0]; tile[i][j4 + 1] = v[1];
    tile[i][j4 + 2] = v[2]; tile[i][j4 + 3] = v[3];
    __syncthreads();
    bf16x4 o;
#pragma unroll
    for (int r = 0; r < 4; ++r) o[r] = (bf16_t)tile[j4 + r][i];
    *(bf16x4*)&g_whhT[(size_t)(c0 + i) * H_ + r0 + j4] = o;
}

// t = 0: h = tanh(x[:,0]*W_hx + b_h); also reset handoff flags.
__global__ __launch_bounds__(256) void rnn_init(const float* __restrict__ x,
                                                const float* __restrict__ Whx,
                                                const float* __restrict__ bh) {
    if (blockIdx.x == 0 && threadIdx.x < 128) g_flag[threadIdx.x] = 0;
    const int gid = blockIdx.x * 256 + threadIdx.x;
    const int row = gid >> 9;
    const int col = (gid & 511) << 2;
    const float xv = x[(size_t)row * T_];
    f32x4 w = *(const f32x4*)&Whx[col];
    f32x4 b = *(const f32x4*)&bh[col];
    bf16x4 o;
#pragma unroll
    for (int j = 0; j < 4; ++j) o[j] = (bf16_t)tanhf(fmaf(xv, w[j], b[j]));
    *(bf16x4*)&g_hb[0][(size_t)row * H_ + col] = o;
}

// Fused split-K RNN step. Grid 256 = 8bm x 16bn x 2kz, 1 block/CU.
// Block: 128x128 tile, K-half 1024, BK=32 (32 iters), 4 waves x 64x64.
// 8-stage LDS ring (128 KB dynamic), 7 stages in flight, vmcnt(24) waits.
// kz0 stores fp32 partials (C-frag layout) and release-publishes a flag;
// kz1 spins, acquires, combines, applies rank-1 + tanh, stores bf16 h.
__global__ __launch_bounds__(256, 1) void rnn_step(const float* __restrict__ x,
                                                   const float* __restrict__ Whx,
                                                   const float* __restrict__ bh,
                                                   int t, int sb, int db) {
    extern __shared__ __align__(16) bf16_t smem[];
    bf16_t* As = smem;               // 8 stages x 4096 elems (8 KB)
    bf16_t* Bs = smem + 8 * 4096;

    const int tid  = threadIdx.x;
    const int lane = tid & 63;
    const int wave = tid >> 6;
    // XCD map: kz = xcd&1 (no K-half mixing per XCD); per-XCD 4bm x 8bn region
    // -> footprint 1 MB A + 2 MB B < 4 MB L2.
    const int li  = blockIdx.x;
    const int xcd = li & 7;
    const int kz  = xcd & 1;
    const int p   = xcd >> 1;              // 0..3
    const int jb  = li >> 3;               // 0..31
    const int bm  = (p & 1) * 4 + (jb & 3);       // 0..7
    const int bn  = (p >> 1) * 8 + (jb >> 2);     // 0..15
    const int tile = bm * 16 + bn;

    const int wm = (wave & 1) * 64, wn = (wave >> 1) * 64;
    const int fr = lane & 15, fq = lane >> 4;

    // Staging: slot s(0..511 per operand) holds row r=s>>2, lds-chunk s&3;
    // global chunk = (s&3) ^ ((r>>1)&3)  (8-row bank spread, 2-way max reads).
    const int rA = tid >> 2;               // 0..63 (second load: +64)
    const int cl = tid & 3;
    const int cg = cl ^ ((rA >> 1) & 3);
    const bf16_t* gpa = g_hb[sb] + (size_t)(bm * 128 + rA) * H_ + kz * 1024 + cg * 8;
    const bf16_t* gpb = g_whhT  + (size_t)(bn * 128 + rA) * H_ + kz * 1024 + cg * 8;

#define ISSUE(SLOT)                                                  \
    do {                                                             \
        gload16(gpa,           As + (SLOT) * 4096 + tid * 8);        \
        gload16(gpa + 64 * H_, As + (SLOT) * 4096 + (tid + 256) * 8);\
        gload16(gpb,           Bs + (SLOT) * 4096 + tid * 8);        \
        gload16(gpb + 64 * H_, Bs + (SLOT) * 4096 + (tid + 256) * 8);\
        gpa += 32; gpb += 32;                                        \
    } while (0)

    // prologue: stages 0..6 (28 loads/thread in flight)
#pragma unroll
    for (int s = 0; s < 7; ++s) ISSUE(s);

    f32x4 acc[4][4];
#pragma unroll
    for (int i = 0; i < 4; ++i)
#pragma unroll
        for (int j = 0; j < 4; ++j) acc[i][j] = (f32x4)(0.f);

    // frag offsets (elems): row*32 + (fq ^ ((row>>1)&3))*8; the XOR term is
    // row-parity-invariant across i/wm (steps of 16/64), so hoist it.
    const int xr = fq ^ ((fr >> 1) & 3);
    int aoff[4], boff[4];
#pragma unroll
    for (int i = 0; i < 4; ++i) {
        aoff[i] = (wm + i * 16 + fr) * 32 + xr * 8;
        boff[i] = (wn + i * 16 + fr) * 32 + xr * 8;
    }

#define COMPUTE(SLOT)                                                       \
    {                                                                       \
        bf16x8 af[4], bfv[4];                                               \
        _Pragma("unroll")                                                   \
        for (int i = 0; i < 4; ++i) {                                       \
            af[i]  = *(const bf16x8*)(As + (SLOT) * 4096 + aoff[i]);        \
            bfv[i] = *(const bf16x8*)(Bs + (SLOT) * 4096 + boff[i]);        \
        }                                                                   \
        _Pragma("unroll")                                                   \
        for (int i = 0; i < 4; ++i)                                         \
            _Pragma("unroll")                                               \
            for (int j = 0; j < 4; ++j)                                     \
                acc[i][j] = __builtin_amdgcn_mfma_f32_16x16x32_bf16(        \
                    af[i], bfv[j], acc[i][j], 0, 0, 0);                     \
    }

    // steady state: iters 0..23 (issue stages 7..30)
    for (int g = 0; g < 3; ++g) {
#pragma unroll
        for (int u = 0; u < 8; ++u) {
            wait_vm_barrier<24>();
            ISSUE((u + 7) & 7);
            COMPUTE(u);
        }
    }
    // iter 24: last issue (stage 31 -> slot 7)
    wait_vm_barrier<24>(); ISSUE(7); COMPUTE(0);
    // drain
    wait_vm_barrier<24>(); COMPUTE(1);
    wait_vm_barrier<20>(); COMPUTE(2);
    wait_vm_barrier<16>(); COMPUTE(3);
    wait_vm_barrier<12>(); COMPUTE(4);
    wait_vm_barrier<8>();  COMPUTE(5);
    wait_vm_barrier<4>();  COMPUTE(6);
    wait_vm_barrier<0>();  COMPUTE(7);
#undef COMPUTE
#undef ISSUE

    float* pbase = &g_part[tile][wave * 4096];
    if (kz == 0) {
        // store partial in C-frag layout: fully coalesced 16B/lane
#pragma unroll
        for (int i = 0; i < 4; ++i)
#pragma unroll
            for (int j = 0; j < 4; ++j)
                *(f32x4*)(pbase + (i * 4 + j) * 256 + lane * 4) = acc[i][j];
        __threadfence();
        __syncthreads();
        if (tid == 0)
            __hip_atomic_store(&g_flag[tile], t, __ATOMIC_RELEASE,
                               __HIP_MEMORY_SCOPE_AGENT);
    } else {
        if (tid == 0) {
            while (__hip_atomic_load(&g_flag[tile], __ATOMIC_RELAXED,
                                     __HIP_MEMORY_SCOPE_AGENT) != t)
                __builtin_amdgcn_s_sleep(1);
        }
        __syncthreads();
        __builtin_amdgcn_fence(__ATOMIC_ACQUIRE, "agent");
#pragma unroll
        for (int i = 0; i < 4; ++i)
#pragma unroll
            for (int j = 0; j < 4; ++j)
                acc[i][j] += *(const f32x4*)(pbase + (i * 4 + j) * 256 + lane * 4);

        // epilogue: + x_t*W_hx + b_h, tanh, bf16 store
        bf16_t* __restrict__ hn = g_hb[db];
#pragma unroll
        for (int i = 0; i < 4; ++i) {
            const int row0 = bm * 128 + wm + i * 16 + fq * 4;
            float xv[4];
#pragma unroll
            for (int r = 0; r < 4; ++r) xv[r] = x[(size_t)(row0 + r) * T_ + t];
#pragma unroll
            for (int j = 0; j < 4; ++j) {
                const int col = bn * 128 + wn + j * 16 + fr;
                const float wv = Whx[col];
                const float bv = bh[col];
#pragma unroll
                for (int r = 0; r < 4; ++r)
                    hn[(size_t)(row0 + r) * H_ + col] =
                        (bf16_t)tanhf(acc[i][j][r] + xv[r] * wv + bv);
            }
        }
    }
}

// p = h_T @ W_ph + b_p : one wave per batch row, fp32 accumulate.
__global__ __launch_bounds__(64) void rnn_proj(const float* __restrict__ Wph,
                                               const float* __restrict__ bp,
                                               float* __restrict__ out, int sb) {
    const int b = blockIdx.x;
    const int l = threadIdx.x;
    const bf16_t* h = g_hb[sb] + (size_t)b * H_;
    float acc[C_];
#pragma unroll
    for (int c = 0; c < C_; ++c) acc[c] = 0.f;
    for (int k = l; k < H_; k += 64) {
        const float hv = (float)h[k];
#pragma unroll
        for (int c = 0; c < C_; ++c)
            acc[c] = fmaf(hv, Wph[k * C_ + c], acc[c]);
    }
#pragma unroll
    for (int off = 32; off > 0; off >>= 1)
#pragma unroll
        for (int c = 0; c < C_; ++c) acc[c] += __shfl_down(acc[c], off);
    if (l == 0) {
#pragma unroll
        for (int c = 0; c < C_; ++c) out[b * C_ + c] = acc[c] + bp[c];
    }
}

extern "C" void kernel_launch(void* const* d_in, const int* in_sizes, int n_in,
                              void* d_out, int out_size, void* d_ws, size_t ws_size,
                              hipStream_t stream) {
    const float* x   = (const float*)d_in[0];   // [1024,128]
    const float* Whx = (const float*)d_in[1];   // [1,2048]
    const float* Whh = (const float*)d_in[2];   // [2048,2048]
    const float* bh  = (const float*)d_in[3];   // [2048]
    const float* Wph = (const float*)d_in[4];   // [2048,10]
    const float* bp  = (const float*)d_in[5];   // [1,10]
    float* out = (float*)d_out;                 // [1024,10]

    static bool attr_set = false;
    if (!attr_set) {
        hipFuncSetAttribute((const void*)rnn_step,
                            hipFuncAttributeMaxDynamicSharedMemorySize, 131072);
        attr_set = true;
    }

    prep_whhT<<<dim3(64, 64), 256, 0, stream>>>(Whh);
    rnn_init<<<(B_ * H_ / 4) / 256, 256, 0, stream>>>(x, Whx, bh);

    int src = 0;
    for (int t = 1; t < T_; ++t) {
        rnn_step<<<256, 256, 131072, stream>>>(x, Whx, bh, t, src, 1 - src);
        src = 1 - src;
    }
    rnn_proj<<<B_, 64, 0, stream>>>(Wph, bp, out, src);
}

// Round 7
// 2636.578 us; speedup vs baseline: 3.1593x; 3.1593x over previous
//
#include <hip/hip_runtime.h>
#include <math.h>

#define B_ 1024
#define T_ 128
#define H_ 2048
#define C_ 10

typedef __bf16 bf16_t;
typedef __bf16 bf16x8 __attribute__((ext_vector_type(8)));
typedef __bf16 bf16x4 __attribute__((ext_vector_type(4)));
typedef float f32x4 __attribute__((ext_vector_type(4)));

// Static device storage: bf16 h ping-pong (8 MB), bf16 W_hh^T (8 MB).
__device__ __align__(16) bf16_t g_hb[2][(size_t)B_ * H_];
__device__ __align__(16) bf16_t g_whhT[(size_t)H_ * H_];

__device__ __forceinline__ void gload16(const bf16_t* g, bf16_t* l) {
    __builtin_amdgcn_global_load_lds(
        (const __attribute__((address_space(1))) void*)g,
        (__attribute__((address_space(3))) void*)l, 16, 0, 0);
}

// Counted-vmcnt barrier: retire oldest pipeline stage without draining.
template <int VM>
__device__ __forceinline__ void wait_vm_barrier() {
    asm volatile("s_waitcnt vmcnt(%0)\n\ts_barrier" :: "n"(VM) : "memory");
}

// One-time: W_hhT[n][k] = bf16(W_hh[k][n]) — B operand must be K-contiguous.
__global__ __launch_bounds__(256) void prep_whhT(const float* __restrict__ Whh) {
    __shared__ float tile[32][33];
    const int i  = threadIdx.x >> 3;
    const int j4 = (threadIdx.x & 7) * 4;
    const int r0 = blockIdx.y * 32;
    const int c0 = blockIdx.x * 32;
    f32x4 v = *(const f32x4*)(Whh + (size_t)(r0 + i) * H_ + c0 + j4);
    tile[i][j4 + 0] = v[0]; tile[i][j4 + 1] = v[1];
    tile[i][j4 + 2] = v[2]; tile[i][j4 + 3] = v[3];
    __syncthreads();
    bf16x4 o;
#pragma unroll
    for (int r = 0; r < 4; ++r) o[r] = (bf16_t)tile[j4 + r][i];
    *(bf16x4*)&g_whhT[(size_t)(c0 + i) * H_ + r0 + j4] = o;
}

// t = 0: h = tanh(x[:,0]*W_hx + b_h)  (h0 == 0) -> bf16
__global__ __launch_bounds__(256) void rnn_init(const float* __restrict__ x,
                                                const float* __restrict__ Whx,
                                                const float* __restrict__ bh) {
    const int gid = blockIdx.x * 256 + threadIdx.x;
    const int row = gid >> 9;
    const int col = (gid & 511) << 2;
    const float xv = x[(size_t)row * T_];
    f32x4 w = *(const f32x4*)&Whx[col];
    f32x4 b = *(const f32x4*)&bh[col];
    bf16x4 o;
#pragma unroll
    for (int j = 0; j < 4; ++j) o[j] = (bf16_t)tanhf(fmaf(xv, w[j], b[j]));
    *(bf16x4*)&g_hb[0][(size_t)row * H_ + col] = o;
}

// Fused RNN step: h[db] = tanh(h[sb] @ W_hh + x[:,t]*W_hx + b_h), bf16 out.
// 128(M)x64(N) block tile, full K, BK=64 (32 iters), grid 256 = 1 block/CU,
// 4 waves x 64x32 wave tile (AI = 21.3 FLOP/LDS-byte; every SIMD on the chip
// owns exactly one wave-tile). 4-stage LDS ring (96 KB dynamic), 3 stages in
// flight, counted-vmcnt barriers (no per-iter drain). XOR k-chunk swizzle
// keeps frag ds_read_b128 at 2-way (free) with the lane-linear staging
// layout global_load_lds requires.
// XCD map: each XCD owns a 4bm x 8bn region -> A 2MB + B 2MB in its L2;
// B half is step-invariant and stays resident across steps.
__global__ __launch_bounds__(256, 1) void rnn_step(const float* __restrict__ x,
                                                   const float* __restrict__ Whx,
                                                   const float* __restrict__ bh,
                                                   int t, int sb, int db) {
    extern __shared__ __align__(16) bf16_t smem[];
    bf16_t* As = smem;                 // 4 stages x 8192 elems (16 KB)
    bf16_t* Bs = smem + 4 * 8192;      // 4 stages x 4096 elems (8 KB)

    const int tid  = threadIdx.x;
    const int lane = tid & 63;
    const int wave = tid >> 6;
    // XCD-region swizzle: xcd = li&7; region = (xcd&1)*4bm x (xcd>>1)*8bn
    const int li = blockIdx.x;
    const int xcd = li & 7;
    const int p   = li >> 3;                         // 0..31
    const int bm  = (xcd & 1) * 4 + (p & 3);         // 0..7
    const int bn  = (xcd >> 1) * 8 + (p >> 2);       // 0..31

    const int wm = (wave & 1) * 64, wn = (wave >> 1) * 32;
    const int fr = lane & 15, fq = lane >> 4;

    // Staging: linear slot s holds row s>>3, lds-chunk s&7;
    // global chunk = (s&7) ^ (row&7)  (8-row spread -> 2-way frag reads).
    const int rA = tid >> 3;                         // 0..31
    const int cg = (tid & 7) ^ (rA & 7);
    const bf16_t* gpa = g_hb[sb] + (size_t)(bm * 128 + rA) * H_ + cg * 8;
    const bf16_t* gpb = g_whhT  + (size_t)(bn * 64  + rA) * H_ + cg * 8;

    // 6 loads/thread/stage: A rows rA, rA+32, rA+64, rA+96; B rows rA, rA+32.
#define ISSUE(SLOT)                                                      \
    do {                                                                 \
        gload16(gpa,            As + (SLOT) * 8192 + tid * 8);           \
        gload16(gpa + 32 * H_,  As + (SLOT) * 8192 + (tid + 256) * 8);   \
        gload16(gpa + 64 * H_,  As + (SLOT) * 8192 + (tid + 512) * 8);   \
        gload16(gpa + 96 * H_,  As + (SLOT) * 8192 + (tid + 768) * 8);   \
        gload16(gpb,            Bs + (SLOT) * 4096 + tid * 8);           \
        gload16(gpb + 32 * H_,  Bs + (SLOT) * 4096 + (tid + 256) * 8);   \
        gpa += 64; gpb += 64;                                            \
    } while (0)

    // prologue: stages 0,1,2 (18 loads/thread in flight)
    ISSUE(0); ISSUE(1); ISSUE(2);

    f32x4 acc[4][2];
#pragma unroll
    for (int i = 0; i < 4; ++i)
#pragma unroll
        for (int j = 0; j < 2; ++j) acc[i][j] = (f32x4)(0.f);

    // frag offsets (elems): row*64 + ((cc*4+fq) ^ (row&7))*8; row&7 == fr&7.
    const int xr0 = (fq ^ (fr & 7)) * 8;
    const int xr1 = ((4 + fq) ^ (fr & 7)) * 8;
    int aoff[4][2], boff[2][2];
#pragma unroll
    for (int i = 0; i < 4; ++i) {
        aoff[i][0] = (wm + i * 16 + fr) * 64 + xr0;
        aoff[i][1] = (wm + i * 16 + fr) * 64 + xr1;
    }
#pragma unroll
    for (int j = 0; j < 2; ++j) {
        boff[j][0] = (wn + j * 16 + fr) * 64 + xr0;
        boff[j][1] = (wn + j * 16 + fr) * 64 + xr1;
    }

#define COMPUTE(SLOT)                                                       \
    {                                                                       \
        _Pragma("unroll")                                                   \
        for (int cc = 0; cc < 2; ++cc) {                                    \
            bf16x8 af[4], bfv[2];                                           \
            _Pragma("unroll")                                               \
            for (int j = 0; j < 2; ++j)                                     \
                bfv[j] = *(const bf16x8*)(Bs + (SLOT) * 4096 + boff[j][cc]);\
            _Pragma("unroll")                                               \
            for (int i = 0; i < 4; ++i)                                     \
                af[i] = *(const bf16x8*)(As + (SLOT) * 8192 + aoff[i][cc]); \
            _Pragma("unroll")                                               \
            for (int i = 0; i < 4; ++i)                                     \
                _Pragma("unroll")                                           \
                for (int j = 0; j < 2; ++j)                                 \
                    acc[i][j] = __builtin_amdgcn_mfma_f32_16x16x32_bf16(    \
                        af[i], bfv[j], acc[i][j], 0, 0, 0);                 \
        }                                                                   \
    }

    // it = 0
    wait_vm_barrier<12>(); ISSUE(3); COMPUTE(0);
    // its 1..28 (issue stages 4..31 into slot u, compute slot (u+1)&3)
    for (int g = 0; g < 7; ++g) {
#pragma unroll
        for (int u = 0; u < 4; ++u) {
            wait_vm_barrier<12>();
            ISSUE(u);
            COMPUTE((u + 1) & 3);
        }
    }
    // drain: its 29,30,31
    wait_vm_barrier<12>(); COMPUTE(1);
    wait_vm_barrier<6>();  COMPUTE(2);
    wait_vm_barrier<0>();  COMPUTE(3);
#undef COMPUTE
#undef ISSUE

    // epilogue: + x_t*W_hx + b_h, tanh, bf16 store
    bf16_t* __restrict__ hn = g_hb[db];
#pragma unroll
    for (int i = 0; i < 4; ++i) {
        const int row0 = bm * 128 + wm + i * 16 + fq * 4;
        float xv[4];
#pragma unroll
        for (int r = 0; r < 4; ++r) xv[r] = x[(size_t)(row0 + r) * T_ + t];
#pragma unroll
        for (int j = 0; j < 2; ++j) {
            const int col = bn * 64 + wn + j * 16 + fr;
            const float wv = Whx[col];
            const float bv = bh[col];
#pragma unroll
            for (int r = 0; r < 4; ++r)
                hn[(size_t)(row0 + r) * H_ + col] =
                    (bf16_t)tanhf(acc[i][j][r] + xv[r] * wv + bv);
        }
    }
}

// p = h_T @ W_ph + b_p : one wave per batch row, fp32 accumulate.
__global__ __launch_bounds__(64) void rnn_proj(const float* __restrict__ Wph,
                                               const float* __restrict__ bp,
                                               float* __restrict__ out, int sb) {
    const int b = blockIdx.x;
    const int l = threadIdx.x;
    const bf16_t* h = g_hb[sb] + (size_t)b * H_;
    float acc[C_];
#pragma unroll
    for (int c = 0; c < C_; ++c) acc[c] = 0.f;
    for (int k = l; k < H_; k += 64) {
        const float hv = (float)h[k];
#pragma unroll
        for (int c = 0; c < C_; ++c)
            acc[c] = fmaf(hv, Wph[k * C_ + c], acc[c]);
    }
#pragma unroll
    for (int off = 32; off > 0; off >>= 1)
#pragma unroll
        for (int c = 0; c < C_; ++c) acc[c] += __shfl_down(acc[c], off);
    if (l == 0) {
#pragma unroll
        for (int c = 0; c < C_; ++c) out[b * C_ + c] = acc[c] + bp[c];
    }
}

extern "C" void kernel_launch(void* const* d_in, const int* in_sizes, int n_in,
                              void* d_out, int out_size, void* d_ws, size_t ws_size,
                              hipStream_t stream) {
    const float* x   = (const float*)d_in[0];   // [1024,128]
    const float* Whx = (const float*)d_in[1];   // [1,2048]
    const float* Whh = (const float*)d_in[2];   // [2048,2048]
    const float* bh  = (const float*)d_in[3];   // [2048]
    const float* Wph = (const float*)d_in[4];   // [2048,10]
    const float* bp  = (const float*)d_in[5];   // [1,10]
    float* out = (float*)d_out;                 // [1024,10]

    static bool attr_set = false;
    if (!attr_set) {
        hipFuncSetAttribute((const void*)rnn_step,
                            hipFuncAttributeMaxDynamicSharedMemorySize, 98304);
        attr_set = true;
    }

    prep_whhT<<<dim3(64, 64), 256, 0, stream>>>(Whh);
    rnn_init<<<(B_ * H_ / 4) / 256, 256, 0, stream>>>(x, Whx, bh);

    int src = 0;
    for (int t = 1; t < T_; ++t) {
        rnn_step<<<256, 256, 98304, stream>>>(x, Whx, bh, t, src, 1 - src);
        src = 1 - src;
    }
    rnn_proj<<<B_, 64, 0, stream>>>(Wph, bp, out, src);
}